// Round 12
// baseline (58752.161 us; speedup 1.0000x reference)
//
#include <hip/hip_runtime.h>
#include <math.h>

typedef _Float16 f16;
typedef _Float16 f16x8 __attribute__((ext_vector_type(8)));
typedef float f32x4 __attribute__((ext_vector_type(4)));
typedef unsigned long long u64;
typedef unsigned short u16;

#define MFMA16 __builtin_amdgcn_mfma_f32_16x16x32_f16

// Wint layout: [ctg 0..79][k8 0..127][lane 0..15][32B: 8 f16 hi | 8 f16 lo]
//   element (col n, k): ctg=n>>4, k8=k>>3, lane=n&15, slot k&7.
// Wih_int: same but k8 0..31 (K=256).

// ---------------- prep kernels ----------------

__global__ __launch_bounds__(256) void prep_copy_x0(const float* __restrict__ x0,
                                                    float* __restrict__ traj,
                                                    f16* __restrict__ xhi,
                                                    f16* __restrict__ xlo) {
    int i = blockIdx.x * 256 + threadIdx.x;  // 65536 total
    float v = x0[i];
    traj[i] = v;
    f16 h = (f16)v;
    xhi[i] = h;
    xlo[i] = (f16)(v - (float)h);
}

// Wih [1024][256] fp32 -> Wih_int interleaved hi/lo
__global__ __launch_bounds__(256) void prep_wih_int(const float* __restrict__ Wih,
                                                    char* __restrict__ Wih_int) {
    int i = blockIdx.x * 256 + threadIdx.x;  // 262144
    int j = i >> 8, k = i & 255;
    float v = Wih[i];
    f16 h = (f16)v;
    char* base = Wih_int + ((size_t)(j >> 4) * 32 + (k >> 3)) * 512 + (j & 15) * 32;
    *(f16*)(base + (k & 7) * 2) = h;
    *(f16*)(base + 16 + (k & 7) * 2) = (f16)(v - (float)h);
}

// Wfc [256][1024] fp32 -> Wint rows 1024..1279 (ctg 64..79)
__global__ __launch_bounds__(256) void prep_wfc_int(const float* __restrict__ Wfc,
                                                    char* __restrict__ Wint) {
    int i = blockIdx.x * 256 + threadIdx.x;  // 262144
    int o = i >> 10, k = i & 1023;
    float v = Wfc[i];
    f16 h = (f16)v;
    char* base = Wint + ((size_t)(64 + (o >> 4)) * 128 + (k >> 3)) * 512 + (o & 15) * 32;
    *(f16*)(base + (k & 7) * 2) = h;
    *(f16*)(base + 16 + (k & 7) * 2) = (f16)(v - (float)h);
}

__global__ __launch_bounds__(256) void prep_bias(const float* __restrict__ bih,
                                                 const float* __restrict__ bhh,
                                                 const float* __restrict__ bfc,
                                                 const float* __restrict__ Wih,
                                                 float* __restrict__ b1,
                                                 float* __restrict__ bcmb) {
    int wave = blockIdx.x * 4 + (threadIdx.x >> 6);  // 64 waves total
    int lane = threadIdx.x & 63;
    for (int j = wave * 16; j < wave * 16 + 16; ++j) {
        float s = 0.f;
        for (int o = lane; o < 256; o += 64) s += bfc[o] * Wih[j * 256 + o];
        for (int off = 32; off; off >>= 1) s += __shfl_down(s, off);
        if (lane == 0) {
            float t = bih[j] + bhh[j];
            b1[j] = t;
            bcmb[j] = t + s;
        }
    }
}

// Wcmb[j][k] = W_hh[j][k] + sum_o W_ih[j][o]*W_fc[o][k] -> Wint ctg 0..63
__global__ __launch_bounds__(256) void prep_wcmb(const float* __restrict__ Wih,
                                                 const float* __restrict__ Wfc,
                                                 const float* __restrict__ Whh,
                                                 char* __restrict__ Wint) {
    __shared__ float As[64][65];
    __shared__ float Bs[64][65];
    int j0 = blockIdx.y * 64, k0 = blockIdx.x * 64;
    int tid = threadIdx.x;
    float acc[4][4] = {};
    for (int o0 = 0; o0 < 256; o0 += 64) {
        __syncthreads();
        #pragma unroll
        for (int i = 0; i < 16; ++i) {
            int e = i * 256 + tid;
            int r = e >> 6, c = e & 63;
            As[r][c] = Wih[(j0 + r) * 256 + o0 + c];
            Bs[r][c] = Wfc[(o0 + r) * 1024 + k0 + c];
        }
        __syncthreads();
        int ty = tid >> 4, tx = tid & 15;
        for (int o = 0; o < 64; ++o) {
            float a[4], b[4];
            #pragma unroll
            for (int i = 0; i < 4; ++i) a[i] = As[ty * 4 + i][o];
            #pragma unroll
            for (int i = 0; i < 4; ++i) b[i] = Bs[o][tx * 4 + i];
            #pragma unroll
            for (int i = 0; i < 4; ++i)
                #pragma unroll
                for (int jj = 0; jj < 4; ++jj) acc[i][jj] += a[i] * b[jj];
        }
    }
    int ty = tid >> 4, tx = tid & 15;
    #pragma unroll
    for (int i = 0; i < 4; ++i)
        #pragma unroll
        for (int jj = 0; jj < 4; ++jj) {
            int j = j0 + ty * 4 + i, k = k0 + tx * 4 + jj;
            float v = acc[i][jj] + Whh[j * 1024 + k];
            f16 h = (f16)v;
            char* base = Wint + ((size_t)(j >> 4) * 128 + (k >> 3)) * 512 + (j & 15) * 32;
            *(f16*)(base + (k & 7) * 2) = h;
            *(f16*)(base + 16 + (k & 7) * 2) = (f16)(v - (float)h);
        }
}

// ---------------- rollout: zero cross-WG communication ----------------
// 16 WGs x 512 threads. WG g owns batch rows g*16..g*16+15 and computes ALL
// 1280 output columns every step; h (hi/lo) lives in this WG's LDS only.
// Wave w owns coltiles ctg = w*10 .. w*10+9 (h: ctg<64, y: ctg>=64).
// MFMA mapping (verified r7-r11): A=W-frag (lane l15 = col), B=h-frag
// (lane l15 = batch row); thread (l15,kq) elem p = C[row l15][col ctg*16+kq*4+p].

__global__ __launch_bounds__(512) void rollout(
    const f16* __restrict__ x0_hi, const f16* __restrict__ x0_lo,
    const char* __restrict__ Wih_int, const char* __restrict__ Wint,
    const float* __restrict__ b1, const float* __restrict__ bcmb,
    const float* __restrict__ bfc, float* __restrict__ traj) {
    __shared__ f16 hs_hi[16 * 1024];  // [row][k], XOR-swizzled, 32 KB
    __shared__ f16 hs_lo[16 * 1024];

    const int g = blockIdx.x;   // row group
    const int tid = threadIdx.x;
    const int lane = tid & 63;
    const int w = tid >> 6;     // 0..7
    const int l15 = lane & 15;
    const int kq = lane >> 4;   // 0..3

    // ---- stage x0 rows into hs (k < 256) ----
    for (int i = tid; i < 4096; i += 512) {
        int r = i >> 8, k = i & 255;
        int byte = (r * 2048 + k * 2) ^ ((r & 7) << 4);
        *(f16*)((char*)hs_hi + byte) = x0_hi[(g * 16 + r) * 256 + k];
        *(f16*)((char*)hs_lo + byte) = x0_lo[(g * 16 + r) * 256 + k];
    }
    __syncthreads();

    // per-wave column metadata
    f32x4 bias[10];
    bool isy[10];
    #pragma unroll
    for (int ct = 0; ct < 10; ++ct) {
        int ctg = w * 10 + ct;
        int c = ctg * 16 + kq * 4;
        isy[ct] = (ctg >= 64);
        bias[ct] = isy[ct] ? *(const f32x4*)&bfc[c - 1024] : *(const f32x4*)&bcmb[c];
    }

    // ---- step 1: h_1 = tanh(x0 @ Wih^T + b1), h-cols only (8 ctg/wave) ----
    {
        f32x4 acc[8] = {};
        for (int kk = 0; kk < 8; ++kk) {
            int byte = (l15 * 2048 + (kk * 32 + kq * 8) * 2) ^ ((l15 & 7) << 4);
            f16x8 hh = *(const f16x8*)((const char*)hs_hi + byte);
            f16x8 hl = *(const f16x8*)((const char*)hs_lo + byte);
            #pragma unroll
            for (int ct = 0; ct < 8; ++ct) {
                const char* p = Wih_int +
                    ((size_t)(w * 8 + ct) * 32 + kk * 4 + kq) * 512 + l15 * 32;
                f16x8 wh = *(const f16x8*)p;
                f16x8 wl = *(const f16x8*)(p + 16);
                acc[ct] = MFMA16(wh, hh, acc[ct], 0, 0, 0);
                acc[ct] = MFMA16(wh, hl, acc[ct], 0, 0, 0);
                acc[ct] = MFMA16(wl, hh, acc[ct], 0, 0, 0);
            }
        }
        __syncthreads();
        #pragma unroll
        for (int ct = 0; ct < 8; ++ct) {
            int c = (w * 8 + ct) * 16 + kq * 4;
            u64 whi = 0, wlo = 0;
            #pragma unroll
            for (int p = 0; p < 4; ++p) {
                float tv = tanhf(acc[ct][p] + b1[c + p]);
                f16 th = (f16)tv;
                f16 tl = (f16)(tv - (float)th);
                whi |= (u64)__builtin_bit_cast(u16, th) << (16 * p);
                wlo |= (u64)__builtin_bit_cast(u16, tl) << (16 * p);
            }
            int byte = (l15 * 2048 + c * 2) ^ ((l15 & 7) << 4);
            *(u64*)((char*)hs_hi + byte) = whi;
            *(u64*)((char*)hs_lo + byte) = wlo;
        }
        __syncthreads();
    }

    // ---- main loop: step t computes h_t (in LDS) and y_{t-1} (global) ----
    for (int t = 2; t <= 511; ++t) {
        f32x4 acc[10] = {};
        #pragma unroll 2
        for (int kk = 0; kk < 32; ++kk) {
            int byte = (l15 * 2048 + (kk * 32 + kq * 8) * 2) ^ ((l15 & 7) << 4);
            f16x8 hh = *(const f16x8*)((const char*)hs_hi + byte);
            f16x8 hl = *(const f16x8*)((const char*)hs_lo + byte);
            #pragma unroll
            for (int ct = 0; ct < 10; ++ct) {
                const char* p = Wint +
                    ((size_t)(w * 10 + ct) * 128 + kk * 4 + kq) * 512 + l15 * 32;
                f16x8 wh = *(const f16x8*)p;
                f16x8 wl = *(const f16x8*)(p + 16);
                acc[ct] = MFMA16(wh, hh, acc[ct], 0, 0, 0);
                acc[ct] = MFMA16(wh, hl, acc[ct], 0, 0, 0);
                acc[ct] = MFMA16(wl, hh, acc[ct], 0, 0, 0);
            }
        }
        __syncthreads();  // all h_{t-1} LDS reads done
        float* ytraj = traj + (size_t)(t - 1) * 65536 + (size_t)(g * 16 + l15) * 256;
        #pragma unroll
        for (int ct = 0; ct < 10; ++ct) {
            int c = (w * 10 + ct) * 16 + kq * 4;
            f32x4 v = acc[ct] + bias[ct];
            if (!isy[ct]) {
                u64 whi = 0, wlo = 0;
                #pragma unroll
                for (int p = 0; p < 4; ++p) {
                    float tv = tanhf(v[p]);
                    f16 th = (f16)tv;
                    f16 tl = (f16)(tv - (float)th);
                    whi |= (u64)__builtin_bit_cast(u16, th) << (16 * p);
                    wlo |= (u64)__builtin_bit_cast(u16, tl) << (16 * p);
                }
                int byte = (l15 * 2048 + c * 2) ^ ((l15 & 7) << 4);
                *(u64*)((char*)hs_hi + byte) = whi;
                *(u64*)((char*)hs_lo + byte) = wlo;
            } else {
                *(f32x4*)&ytraj[c - 1024] = v;
            }
        }
        __syncthreads();  // h_t visible before next step's reads
    }

    // ---- final: y_511 from h_511 (waves holding y-tiles only) ----
    bool anyy = (w * 10 + 9 >= 64);
    if (anyy) {
        f32x4 acc[10] = {};
        for (int kk = 0; kk < 32; ++kk) {
            int byte = (l15 * 2048 + (kk * 32 + kq * 8) * 2) ^ ((l15 & 7) << 4);
            f16x8 hh = *(const f16x8*)((const char*)hs_hi + byte);
            f16x8 hl = *(const f16x8*)((const char*)hs_lo + byte);
            #pragma unroll
            for (int ct = 0; ct < 10; ++ct) {
                if (!isy[ct]) continue;
                const char* p = Wint +
                    ((size_t)(w * 10 + ct) * 128 + kk * 4 + kq) * 512 + l15 * 32;
                f16x8 wh = *(const f16x8*)p;
                f16x8 wl = *(const f16x8*)(p + 16);
                acc[ct] = MFMA16(wh, hh, acc[ct], 0, 0, 0);
                acc[ct] = MFMA16(wh, hl, acc[ct], 0, 0, 0);
                acc[ct] = MFMA16(wl, hh, acc[ct], 0, 0, 0);
            }
        }
        float* ytraj = traj + (size_t)511 * 65536 + (size_t)(g * 16 + l15) * 256;
        #pragma unroll
        for (int ct = 0; ct < 10; ++ct) {
            if (!isy[ct]) continue;
            int c = (w * 10 + ct) * 16 + kq * 4;
            f32x4 v = acc[ct] + bias[ct];
            *(f32x4*)&ytraj[c - 1024] = v;
        }
    }
}

// ---------------- launch ----------------

extern "C" void kernel_launch(void* const* d_in, const int* in_sizes, int n_in,
                              void* d_out, int out_size, void* d_ws, size_t ws_size,
                              hipStream_t stream) {
    const float* x0 = (const float*)d_in[0];
    const float* Wih = (const float*)d_in[1];
    const float* bih = (const float*)d_in[2];
    const float* Whh = (const float*)d_in[3];
    const float* bhh = (const float*)d_in[4];
    const float* Wfc = (const float*)d_in[5];
    const float* bfc = (const float*)d_in[6];
    float* traj = (float*)d_out;  // [512][256][256]

    char* w = (char*)d_ws;
    size_t off = 0;
    char* Wint = w + off;            off += 80u * 128 * 16 * 32;  // 5,242,880
    char* Wih_int = w + off;         off += 64u * 32 * 16 * 32;   // 1,048,576
    f16* x0_hi = (f16*)(w + off);    off += 256u * 256 * 2;
    f16* x0_lo = (f16*)(w + off);    off += 256u * 256 * 2;
    float* b1 = (float*)(w + off);   off += 4096;
    float* bcmb = (float*)(w + off); off += 4096;

    prep_copy_x0<<<dim3(256), dim3(256), 0, stream>>>(x0, traj, x0_hi, x0_lo);
    prep_wih_int<<<dim3(1024), dim3(256), 0, stream>>>(Wih, Wih_int);
    prep_wfc_int<<<dim3(1024), dim3(256), 0, stream>>>(Wfc, Wint);
    prep_bias<<<dim3(16), dim3(256), 0, stream>>>(bih, bhh, bfc, Wih, b1, bcmb);
    prep_wcmb<<<dim3(16, 16), dim3(256), 0, stream>>>(Wih, Wfc, Whh, Wint);

    // 16 independent WGs (one per 16-row batch slice). No cross-WG sync,
    // no flags, no fences: each WG streams W from L2 and keeps h in LDS.
    rollout<<<dim3(16), dim3(512), 0, stream>>>(
        x0_hi, x0_lo, Wih_int, Wint, b1, bcmb, bfc, traj);
}